// Round 9
// baseline (9542.007 us; speedup 1.0000x reference)
//
#include <hip/hip_runtime.h>
#include <cstdint>
#include <cstddef>

#define Hn 256
#define Sn 2048
#define Bn 128
#define NT 1024

typedef _Float16 half2_t __attribute__((ext_vector_type(2)));

__device__ __forceinline__ half2_t bc2_(unsigned int u){ return __builtin_bit_cast(half2_t, u); }

__device__ __forceinline__ float fdot2_(half2_t a, half2_t b, float c){
#if __has_builtin(__builtin_amdgcn_fdot2)
  return __builtin_amdgcn_fdot2(a, b, c, false);
#else
  float d;
  asm volatile("v_dot2_f32_f16 %0, %1, %2, %3" : "=v"(d) : "v"(a), "v"(b), "v"(c));
  return d;
#endif
}

__device__ __forceinline__ half2_t pkrtz_(float a, float b){
  return __builtin_bit_cast(half2_t, __builtin_amdgcn_cvt_pkrtz(a, b));
}

// quad (4-lane) sum via DPP quad_perm — all 4 lanes receive the total
__device__ __forceinline__ float qsum_(float v){
  int x = __builtin_bit_cast(int, v);
  int y = __builtin_amdgcn_mov_dpp(x, 0xB1, 0xF, 0xF, true);   // [1,0,3,2]
  v += __builtin_bit_cast(float, y);
  x = __builtin_bit_cast(int, v);
  y = __builtin_amdgcn_mov_dpp(x, 0x4E, 0xF, 0xF, true);       // [2,3,0,1]
  return v + __builtin_bit_cast(float, y);
}

__device__ __forceinline__ float sigmoid_(float v){ return 1.0f/(1.0f+__expf(-v)); }
__device__ __forceinline__ float tanh_(float v){
  float e = __expf(-2.0f*__builtin_fabsf(v));
  float r = (1.0f-e)/(1.0f+e);
  return __builtin_copysignf(r, v);
}

#define F32_(M) M(0) M(1) M(2) M(3) M(4) M(5) M(6) M(7) M(8) M(9) M(10) M(11) \
  M(12) M(13) M(14) M(15) M(16) M(17) M(18) M(19) M(20) M(21) M(22) M(23) \
  M(24) M(25) M(26) M(27) M(28) M(29) M(30) M(31)

// 1024 thr/block, 1 block/CU (97 KB LDS). Thread t: j=t>>2, kq=t&3; owns
// K-quarter [64kq,64kq+64) of rows {j, j+256, j+512}. r,z rows in 64 AGPRs,
// n-row 16 dwords VGPR + 16 dwords LDS (round-8 residency, proven).
// NEW: ONE barrier/step. Quad-redundant gate math (qsum gives all 4 lanes the
// full sums) -> no PRE/gate phase; h double-buffered in LDS. Heads for step
// s-1 run on rotating wave (s&15) before its dot -> hidden under other waves.
__global__ void __launch_bounds__(NT)
bio_rnn(const float* __restrict__ x,
        const float* __restrict__ w_ih, const float* __restrict__ w_hh,
        const float* __restrict__ b_ih, const float* __restrict__ b_hh,
        const float* __restrict__ w_gain, const float* __restrict__ b_gain,
        const float* __restrict__ w_bias, const float* __restrict__ b_bias,
        const float* __restrict__ w_reflex, const float* __restrict__ b_reflex,
        const float* __restrict__ w_policy, const float* __restrict__ b_policy,
        const float* __restrict__ w_motor, const float* __restrict__ b_motor,
        float* __restrict__ y_out, float* __restrict__ router)
{
  const int b  = blockIdx.x;
  const int t  = threadIdx.x;
  const int kq = t & 3;
  const int j  = t >> 2;
  const int l  = t & 63;

  __shared__ unsigned int WL[NT * 20];                 // n-row cols[32:64), 80 B stride
  __shared__ __align__(16) unsigned char hraw[2*640];  // h f16 double buffer; 4 chunks x 160 B
  __shared__ float HW[13][Hn];                         // head weights
  __shared__ float SB[10];                             // head biases

  // ---- AGPR weights: r,z rows, 32 dwords each ----
#define DAG(i) unsigned agr##i, agz##i;
  F32_(DAG)
#undef DAG
  {
    const float* wrR = w_hh + (size_t)(j      )*Hn + kq*64;
    const float* wrZ = w_hh + (size_t)(j + Hn )*Hn + kq*64;
#define WAG(i) { unsigned pr = __builtin_bit_cast(unsigned, pkrtz_(wrR[2*i], wrR[2*i+1])); \
                 unsigned pz = __builtin_bit_cast(unsigned, pkrtz_(wrZ[2*i], wrZ[2*i+1])); \
                 asm("v_accvgpr_write_b32 %0, %1" : "=a"(agr##i) : "v"(pr)); \
                 asm("v_accvgpr_write_b32 %0, %1" : "=a"(agz##i) : "v"(pz)); }
    F32_(WAG)
#undef WAG
  }
  // ---- n-row: cols[0:32) in VGPRs, cols[32:64) in LDS ----
  uint4 WR0, WR1, WR2, WR3;
  {
    const float* wrN = w_hh + (size_t)(j + 2*Hn)*Hn + kq*64;
#define PK(m) __builtin_bit_cast(unsigned, pkrtz_(wrN[2*(m)], wrN[2*(m)+1]))
    WR0 = (uint4){PK(0),PK(1),PK(2),PK(3)};
    WR1 = (uint4){PK(4),PK(5),PK(6),PK(7)};
    WR2 = (uint4){PK(8),PK(9),PK(10),PK(11)};
    WR3 = (uint4){PK(12),PK(13),PK(14),PK(15)};
    #pragma unroll
    for (int i = 0; i < 16; i++)
      WL[t*20 + i] = __builtin_bit_cast(unsigned, pkrtz_(wrN[32+2*i], wrN[32+2*i+1]));
#undef PK
  }
  // gi fold: kq 0/1/2 carry x-dims {2kq,2kq+1}; kq==3 carries the biases.
  half2_t wi0, wi1, wi2; float bd0, bd1, bd2, bd3;
  {
    half2_t z; z.x=(_Float16)0.f; z.y=(_Float16)0.f;
    wi0=z; wi1=z; wi2=z; bd0=bd1=bd2=bd3=0.f;
    if (kq < 3){
      wi0 = pkrtz_(w_ih[(size_t)(j       )*6+2*kq], w_ih[(size_t)(j       )*6+2*kq+1]);
      wi1 = pkrtz_(w_ih[(size_t)(j +  Hn )*6+2*kq], w_ih[(size_t)(j +  Hn )*6+2*kq+1]);
      wi2 = pkrtz_(w_ih[(size_t)(j + 2*Hn)*6+2*kq], w_ih[(size_t)(j + 2*Hn)*6+2*kq+1]);
    } else {
      bd0 = b_ih[j]      + b_hh[j];
      bd1 = b_ih[j+Hn]   + b_hh[j+Hn];
      bd2 = b_hh[j+2*Hn];                 // gh_n bias
      bd3 = b_ih[j+2*Hn];                 // gi_n bias
    }
  }
  if (t < Hn){
    HW[0][t] = w_gain[t];        HW[1][t]  = w_gain[Hn + t];
    HW[2][t] = w_bias[t];        HW[3][t]  = w_bias[Hn + t];
    HW[4][t] = w_bias[2*Hn + t]; HW[5][t]  = w_bias[3*Hn + t];
    HW[6][t] = w_reflex[2*t];    HW[7][t]  = w_reflex[2*t + 1];
    HW[8][t] = b_reflex[t];
    HW[9][t] = w_policy[t];      HW[10][t] = w_policy[Hn + t];
    HW[11][t] = w_motor[t];      HW[12][t] = w_motor[Hn + t];
  }
  if (t < 320) ((unsigned int*)hraw)[t] = 0u;   // zero both h buffers
  if (t == 0){
    SB[0]=b_gain[0]; SB[1]=b_gain[1];
    SB[2]=b_bias[0]; SB[3]=b_bias[1]; SB[4]=b_bias[2]; SB[5]=b_bias[3];
    SB[6]=b_policy[0]; SB[7]=b_policy[1]; SB[8]=b_motor[0]; SB[9]=b_motor[1];
  }
  float hprev = 0.f;
  __syncthreads();

  const float* xg  = x + (size_t)b * Sn * 6;
  const float* xq  = xg + 2*((kq < 3) ? kq : 0);   // this thread's x-pair
  float* rbase     = router + (size_t)b * Sn * Hn;
  const uint4* WLv = (const uint4*)WL;

  // heads for step sprev, entirely within one wave (lane l handles h-indices
  // {2l, 2l+1, 128+2l, 128+2l+1}); lane 0 writes y[sprev].
  auto heads = [&](int sprev, const unsigned* hb){
    const int dw0 = l + ((l >> 5) << 3);
    unsigned hp0 = hb[dw0];            // h[2l], h[2l+1]
    unsigned hp1 = hb[80 + dw0];       // h[128+2l], h[128+2l+1]
    half2_t h01 = bc2_(hp0), h23 = bc2_(hp1);
    float h0=(float)h01.x, h1=(float)h01.y, h2=(float)h23.x, h3=(float)h23.y;
    float p[6];
    #pragma unroll
    for (int g = 0; g < 6; g++){
      float2 wa = *(const float2*)&HW[g][2*l];
      float2 wb = *(const float2*)&HW[g][128+2*l];
      p[g] = h0*wa.x + h1*wa.y + h2*wb.x + h3*wb.y;
    }
    #pragma unroll
    for (int off = 32; off >= 1; off >>= 1){
      p[0]+=__shfl_xor(p[0],off); p[1]+=__shfl_xor(p[1],off); p[2]+=__shfl_xor(p[2],off);
      p[3]+=__shfl_xor(p[3],off); p[4]+=__shfl_xor(p[4],off); p[5]+=__shfl_xor(p[5],off);
    }
    float g0 = sigmoid_(p[0] + SB[0]);
    float g1 = sigmoid_(p[1] + SB[1]);
    float2 xr = *(const float2*)(xg + (size_t)sprev*6);
    float u0 = xr.x * g0, u1 = xr.y * g1;
    float2 w6a = *(const float2*)&HW[6][2*l], w6b = *(const float2*)&HW[6][128+2*l];
    float2 w7a = *(const float2*)&HW[7][2*l], w7b = *(const float2*)&HW[7][128+2*l];
    float2 w8a = *(const float2*)&HW[8][2*l], w8b = *(const float2*)&HW[8][128+2*l];
    float f0 = fmaxf(u0*w6a.x + u1*w7a.x + w8a.x, 0.f);
    float f1 = fmaxf(u0*w6a.y + u1*w7a.y + w8a.y, 0.f);
    float f2 = fmaxf(u0*w6b.x + u1*w7b.x + w8b.x, 0.f);
    float f3 = fmaxf(u0*w6b.y + u1*w7b.y + w8b.y, 0.f);
    float q[4];
    #pragma unroll
    for (int g = 0; g < 4; g++){
      float2 wa = *(const float2*)&HW[9+g][2*l];
      float2 wb = *(const float2*)&HW[9+g][128+2*l];
      q[g] = f0*wa.x + f1*wa.y + f2*wb.x + f3*wb.y;
    }
    #pragma unroll
    for (int off = 32; off >= 1; off >>= 1){
      q[0]+=__shfl_xor(q[0],off); q[1]+=__shfl_xor(q[1],off);
      q[2]+=__shfl_xor(q[2],off); q[3]+=__shfl_xor(q[3],off);
    }
    if (l == 0){
      float4 o;
      o.x = q[0] + SB[6] + (p[2] + SB[2]);
      o.y = q[1] + SB[7] + (p[3] + SB[3]);
      o.z = tanh_(q[2] + SB[8] + (p[4] + SB[4]));
      o.w = tanh_(q[3] + SB[9] + (p[5] + SB[5]));
      *(float4*)(y_out + (size_t)b * Sn * 4 + (size_t)sprev * 4) = o;
    }
  };

#define GCH(c, nv_, r0,r1,r2,r3) { \
    const uint4 Hc = hc4[c]; const uint4 Nw = (nv_); \
    unsigned u0,u1,u2,u3,v0,v1,v2,v3; \
    asm("v_accvgpr_read_b32 %0, %1" : "=v"(u0) : "a"(agr##r0)); \
    asm("v_accvgpr_read_b32 %0, %1" : "=v"(u1) : "a"(agr##r1)); \
    asm("v_accvgpr_read_b32 %0, %1" : "=v"(u2) : "a"(agr##r2)); \
    asm("v_accvgpr_read_b32 %0, %1" : "=v"(u3) : "a"(agr##r3)); \
    asm("v_accvgpr_read_b32 %0, %1" : "=v"(v0) : "a"(agz##r0)); \
    asm("v_accvgpr_read_b32 %0, %1" : "=v"(v1) : "a"(agz##r1)); \
    asm("v_accvgpr_read_b32 %0, %1" : "=v"(v2) : "a"(agz##r2)); \
    asm("v_accvgpr_read_b32 %0, %1" : "=v"(v3) : "a"(agz##r3)); \
    a0=fdot2_(bc2_(u0),bc2_(Hc.x),a0); a1=fdot2_(bc2_(v0),bc2_(Hc.x),a1); a2=fdot2_(bc2_(Nw.x),bc2_(Hc.x),a2); \
    a0=fdot2_(bc2_(u1),bc2_(Hc.y),a0); a1=fdot2_(bc2_(v1),bc2_(Hc.y),a1); a2=fdot2_(bc2_(Nw.y),bc2_(Hc.y),a2); \
    a0=fdot2_(bc2_(u2),bc2_(Hc.z),a0); a1=fdot2_(bc2_(v2),bc2_(Hc.z),a1); a2=fdot2_(bc2_(Nw.z),bc2_(Hc.z),a2); \
    a0=fdot2_(bc2_(u3),bc2_(Hc.w),a0); a1=fdot2_(bc2_(v3),bc2_(Hc.w),a1); a2=fdot2_(bc2_(Nw.w),bc2_(Hc.w),a2); }

  float2 px = *(const float2*)xq;       // prefetched x-pair for step 0
  unsigned cur = 0;

  for (int s = 0; s < Sn; s++){
    const unsigned char* hb = hraw + cur*640;   // h[s-1]
    unsigned char* hw = hraw + (cur^1)*640;     // h[s] destination

    if (s > 0 && (t >> 6) == (s & 15)) heads(s-1, (const unsigned*)hb);

    half2_t xpk = pkrtz_(px.x, px.y);
    if (s + 1 < Sn) px = *(const float2*)(xq + 6);
    xq += 6;

    float a0 = fdot2_(wi0, xpk, bd0);   // r
    float a1 = fdot2_(wi1, xpk, bd1);   // z
    float a2 = bd2;                     // gh_n
    float a3 = fdot2_(wi2, xpk, bd3);   // gi_n

    const uint4* hc4 = (const uint4*)(hb + kq*160);
    const int wlb = t*5;
    GCH(0, WR0,  0, 1, 2, 3)
    GCH(1, WR1,  4, 5, 6, 7)
    GCH(2, WR2,  8, 9,10,11)
    GCH(3, WR3, 12,13,14,15)
    GCH(4, WLv[wlb+0], 16,17,18,19)
    GCH(5, WLv[wlb+1], 20,21,22,23)
    GCH(6, WLv[wlb+2], 24,25,26,27)
    GCH(7, WLv[wlb+3], 28,29,30,31)

    a0 = qsum_(a0); a1 = qsum_(a1); a2 = qsum_(a2); a3 = qsum_(a3);

    // quad-redundant gate math — no barrier, no PRE round-trip
    float r = sigmoid_(a0);
    float z = sigmoid_(a1);
    float n = tanh_(a3 + r*a2);
    float h = (1.f - z)*n + z*hprev;
    hprev = h;
    if (kq == 0){
      *(_Float16*)(hw + (j>>6)*160 + (j&63)*2) = (_Float16)h;
      rbase[(size_t)s*Hn + j] = h;
    }
    __syncthreads();
    cur ^= 1;
  }
  if ((t >> 6) == 0) heads(Sn-1, (const unsigned*)(hraw + cur*640));
#undef GCH
}

extern "C" void kernel_launch(void* const* d_in, const int* in_sizes, int n_in,
                              void* d_out, int out_size, void* d_ws, size_t ws_size,
                              hipStream_t stream)
{
  const float* x        = (const float*)d_in[0];
  const float* w_ih     = (const float*)d_in[1];
  const float* w_hh     = (const float*)d_in[2];
  const float* b_ih     = (const float*)d_in[3];
  const float* b_hh     = (const float*)d_in[4];
  const float* w_gain   = (const float*)d_in[5];
  const float* b_gain   = (const float*)d_in[6];
  const float* w_bias   = (const float*)d_in[7];
  const float* b_bias   = (const float*)d_in[8];
  const float* w_reflex = (const float*)d_in[9];
  const float* b_reflex = (const float*)d_in[10];
  const float* w_policy = (const float*)d_in[11];
  const float* b_policy = (const float*)d_in[12];
  const float* w_motor  = (const float*)d_in[13];
  const float* b_motor  = (const float*)d_in[14];

  float* y_out  = (float*)d_out;
  float* router = (float*)d_out + (size_t)Bn * Sn * 4;

  bio_rnn<<<dim3(Bn), dim3(NT), 0, stream>>>(
      x, w_ih, w_hh, b_ih, b_hh, w_gain, b_gain, w_bias, b_bias,
      w_reflex, b_reflex, w_policy, b_policy, w_motor, b_motor,
      y_out, router);
}